// Round 4
// baseline (205.561 us; speedup 1.0000x reference)
//
#include <hip/hip_runtime.h>
#include <stdint.h>

typedef __attribute__((ext_vector_type(8)))  short  short8;
typedef __attribute__((ext_vector_type(8)))  __bf16 bf16x8;
typedef __attribute__((ext_vector_type(16))) float  floatx16;
typedef __attribute__((ext_vector_type(4)))  float  floatx4;
typedef __attribute__((ext_vector_type(2)))  float  float2v;
typedef __attribute__((ext_vector_type(4)))  uint32_t uint4v;

union Frag { short8 s; bf16x8 v; uint4v d; };
union FU   { float f; uint32_t u; };

// round-to-nearest-even f32 -> bf16 (setup only)
__device__ __forceinline__ short f2bf(float f) {
    FU x; x.f = f;
    uint32_t r = x.u + 0x7fffu + ((x.u >> 16) & 1u);
    return (short)(r >> 16);
}

// pack two f32 -> bf16x2 dword, round-half-up: 2 adds + 1 v_perm
__device__ __forceinline__ uint32_t pack_bf2(float lo, float hi) {
    FU a, b; a.f = lo; b.f = hi;
    return __builtin_amdgcn_perm(b.u + 0x8000u, a.u + 0x8000u, 0x07060302u);
}

__device__ __forceinline__ float fexp2(float x) { return __builtin_amdgcn_exp2f(x); }
__device__ __forceinline__ float frcp(float x)  { return __builtin_amdgcn_rcpf(x); }

// T = exp2(min(arg,15)) + 1 for the pair (acc[j], acc[j+8]).
// No lower clamp: exp2 underflow -> 0 -> T=1 is the exact limit.
// Upper clamp 15 keeps the 8-way product <= 2^121 (no overflow);
// tanh error at the clamp ~6e-5, far under tolerance.
__device__ __forceinline__ float2v tpair(float a, float b) {
    float2v t;
    t.x = fexp2(fminf(a, 15.0f));
    t.y = fexp2(fminf(b, 15.0f));
    return t + 1.0f;
}

// tanh-sum for one tile given B-fragment and table pointers (R12 body).
__device__ __forceinline__ float tile_compute(
    const Frag (&af)[2], const Frag& bfr,
    const floatx4* cq, const floatx4* nq)
{
    float ya = 0.0f;
    #pragma unroll
    for (int h = 0; h < 2; ++h) {
        union { floatx16 v; floatx4 q[4]; } C;
        C.q[0] = cq[h * 4 + 0]; C.q[1] = cq[h * 4 + 1];
        C.q[2] = cq[h * 4 + 2]; C.q[3] = cq[h * 4 + 3];
        floatx16 acc = __builtin_amdgcn_mfma_f32_32x32x16_bf16(
            af[h].v, bfr.v, C.v, 0, 0, 0);

        union { floatx4 q; float2v p[2]; } N0, N1, N2, N3;
        N0.q = nq[h * 4 + 0];   // nb[j=0], nb[j=1]
        N1.q = nq[h * 4 + 1];   // nb[j=2], nb[j=3]
        N2.q = nq[h * 4 + 2];   // nb[j=4], nb[j=5]
        N3.q = nq[h * 4 + 3];   // nb[j=6], nb[j=7]

        float2v T0 = tpair(acc[0], acc[8]);
        float2v T1 = tpair(acc[1], acc[9]);
        float2v P01 = T0 * T1;
        float2v n01 = N0.p[0] * T1 + N0.p[1] * T0;
        float2v T2 = tpair(acc[2], acc[10]);
        float2v T3 = tpair(acc[3], acc[11]);
        float2v P23 = T2 * T3;
        float2v n23 = N1.p[0] * T3 + N1.p[1] * T2;
        float2v T4 = tpair(acc[4], acc[12]);
        float2v T5 = tpair(acc[5], acc[13]);
        float2v P45 = T4 * T5;
        float2v n45 = N2.p[0] * T5 + N2.p[1] * T4;
        float2v T6 = tpair(acc[6], acc[14]);
        float2v T7 = tpair(acc[7], acc[15]);
        float2v P67 = T6 * T7;
        float2v n67 = N3.p[0] * T7 + N3.p[1] * T6;

        float2v PA = P01 * P23, PB = P45 * P67;
        float2v nA = n01 * P23 + n23 * P01;
        float2v nB = n45 * P67 + n67 * P45;
        float2v P  = PA * PB;
        float2v Num = nA * PB + nB * PA;
        float2v R; R.x = frcp(P.x); R.y = frcp(P.y);
        float2v Yh = Num * R;
        ya += Yh.x + Yh.y;
    }
    return ya;
}

// one pipeline step for slot S: consume zb[S] (tile t), refill zb[S] with
// tile t+3W (clamped), compute+store, advance t += W.
template<int S>
__device__ __forceinline__ void tile_step(
    floatx4 (&zb)[3][2], int& t, int W, int tlast, const float* zp,
    const Frag (&af)[2], const floatx4* cqg, const floatx4* nqg,
    float base, float* __restrict__ out, int m, int g)
{
    Frag bfr;   // consuming zb[S] waits only on its own loads; other
    bfr.d[0] = pack_bf2(zb[S][0].x, zb[S][0].y);   // slots stay in flight
    bfr.d[1] = pack_bf2(zb[S][0].z, zb[S][0].w);
    bfr.d[2] = pack_bf2(zb[S][1].x, zb[S][1].y);
    bfr.d[3] = pack_bf2(zb[S][1].z, zb[S][1].w);

    {   // refill immediately: keeps 2-3 loads outstanding at all times
        int tn = t + 3 * W; if (tn > tlast) tn = tlast;   // benign dup
        const float* q = zp + (size_t)tn * 512;
        zb[S][0] = *(const floatx4*)q;
        zb[S][1] = *(const floatx4*)(q + 4);
    }

    // laundered per-tile index: forces fresh LDS broadcast reads so the
    // constant tables never become resident VGPRs (occupancy > residency)
    int zz = 0;
    asm volatile("" : "+v"(zz));
    float ya = tile_compute(af, bfr, cqg + zz, nqg + zz);

    float ov = __shfl_xor(ya, 32, 64);
    if (g == 0) out[(size_t)t * 32 + m] = base + ya + ov;
    t += W;
}

// y[b] = a0 + sum_k bk[k] * tanh(ck[k,:].z[b,:] + dk[k])
//
// D = mfma_32x32x16_bf16(A=s*ck, B=z, C=s*dk) -> D[node][row] = s*(dot+dk),
// s = 2*log2(e); col(lane&31)=batch row, node=(reg&3)+8*(reg>>2)+4*(lane>>5).
// tanh(t) = 1 - 2/(exp2(s*t)+1); 8-way shared denominator per half.
//
// R13 theory (duty cycle, not occupancy): R0 counters show ~26us of VALU
// work inside an ~83us dispatch with avg outstanding bytes/CU ~= 1.3KB --
// waves spend most wall time neither computing nor holding loads in
// flight. Cause: short-lived waves whose ~800cy preamble (ck waits, table
// build, serial shfl reduce) precedes only 2 tiles of work; load windows
// don't tile time (convoy). Fix = copy-ubench shape:
//  - PERSISTENT waves: grid-stride tile loop, 8 tiles/wave at B=2M;
//    preamble amortized to ~100cy/tile.
//  - depth-3 rolling register pipeline ACROSS the loop (triple-unrolled,
//    compile-time slots): every wave holds 2-3KB outstanding at every
//    instant -> 24 waves/CU * ~2.5KB ~= 60KB/CU continuously in flight.
//  - R12 VGPR diet kept (per-wave LDS tables, laundered broadcast reads,
//    no barrier, z youngest) -> __launch_bounds__(256,6), 6 waves/SIMD.
//  - per-tile fire-and-forget store.
// Steady state/CU: VALU+trans ~290cy/tile (31us total) vs mem 21us ->
// predicted kernel 35-45us.
__global__ __launch_bounds__(256, 6) void mave_kernel(
    const float* __restrict__ z,
    const float* __restrict__ a0,
    const float* __restrict__ bk,
    const float* __restrict__ ck,
    const float* __restrict__ dk,
    float* __restrict__ out,
    int ntiles)
{
    const int lane = threadIdx.x & 63;
    const int m    = lane & 31;
    const int g    = lane >> 5;
    const int widx = threadIdx.x >> 6;
    const float S  = 2.885390081777927f;  // 2*log2(e)

    // per-WAVE table copies: no cross-wave sharing -> no __syncthreads
    __shared__ __align__(16) float   cinitL[4][2][2][16];  // [wave][g][h][reg]
    __shared__ __align__(16) float2v nbL[4][2][2][8];      // [wave][g][h][j]

    const int W   = (int)(gridDim.x << 2);                 // total waves
    const int wid = (int)(blockIdx.x * 4 + widx);
    if (wid >= ntiles) return;
    const int tlast = ntiles - 1;
    const int iters = (tlast - wid) / W + 1;

    // ---- loads, oldest first: ck (A fragments) ----
    const float* c0 = ck + m * 16 + g * 8;
    floatx4 ckv0 = *(const floatx4*)c0;
    floatx4 ckv1 = *(const floatx4*)(c0 + 4);
    floatx4 ckv2 = *(const floatx4*)(c0 + 512);
    floatx4 ckv3 = *(const floatx4*)(c0 + 516);

    // ---- table sources (per-lane gathers; tiny, L1/L2-hot) ----
    const int tl = lane;
    const int gg = tl >> 5, hh = (tl >> 4) & 1, rr = tl & 15;
    const int nc = (rr & 3) + 8 * (rr >> 2) + 4 * gg + 32 * hh;
    float dkv = dk[nc];
    float bkt = bk[tl];
    const int g2 = tl >> 4, h2 = (tl >> 3) & 1, j2 = tl & 7;
    const int nl = (j2 & 3) + 8 * (j2 >> 2) + 4 * g2 + 32 * h2;
    float bnl = 0.0f, bnh = 0.0f;
    if (tl < 32) { bnl = bk[nl]; bnh = bk[nl + 16]; }   // exec-masked
    float a0v = a0[0];

    // ---- z pipeline, slots for tiles wid, wid+W, wid+2W (youngest) ----
    const float* zp = z + (size_t)m * 16 + g * 8;
    floatx4 zb[3][2];
    #pragma unroll
    for (int i = 0; i < 3; ++i) {
        int ti = wid + i * W; if (ti > tlast) ti = tlast;   // benign dup
        const float* q = zp + (size_t)ti * 512;
        zb[i][0] = *(const floatx4*)q;
        zb[i][1] = *(const floatx4*)(q + 4);
    }

    // ---- consume ck (wait covers only ck; z stays in flight) ----
    Frag af[2];
    #pragma unroll
    for (int e = 0; e < 4; ++e) {
        af[0].s[e]     = f2bf(ckv0[e] * S);
        af[0].s[e + 4] = f2bf(ckv1[e] * S);
        af[1].s[e]     = f2bf(ckv2[e] * S);
        af[1].s[e + 4] = f2bf(ckv3[e] * S);
    }

    // ---- per-wave tables; same-wave RAW ordered by lgkmcnt only ----
    cinitL[widx][gg][hh][rr] = S * dkv;
    if (tl < 32) {
        float2v nb; nb.x = -2.0f * bnl; nb.y = -2.0f * bnh;
        nbL[widx][g2][h2][j2] = nb;
    }
    float bv = bkt;
    #pragma unroll
    for (int d = 1; d < 64; d <<= 1) bv += __shfl_xor(bv, d, 64);
    const float base = a0v + bv;   // all lanes hold it

    const floatx4* cqg = (const floatx4*)&cinitL[widx][g][0][0];  // 8 quads
    const floatx4* nqg = (const floatx4*)&nbL[widx][g][0][0];     // 8 quads

    // ---- persistent rolling loop: 1 tile/step, slots rotate 0,1,2 ----
    int t   = wid;
    int rem = iters;
    for (;;) {
        tile_step<0>(zb, t, W, tlast, zp, af, cqg, nqg, base, out, m, g);
        if (--rem == 0) break;
        tile_step<1>(zb, t, W, tlast, zp, af, cqg, nqg, base, out, m, g);
        if (--rem == 0) break;
        tile_step<2>(zb, t, W, tlast, zp, af, cqg, nqg, base, out, m, g);
        if (--rem == 0) break;
    }
}

extern "C" void kernel_launch(void* const* d_in, const int* in_sizes, int n_in,
                              void* d_out, int out_size, void* d_ws, size_t ws_size,
                              hipStream_t stream) {
    const float* z  = (const float*)d_in[0];
    const float* a0 = (const float*)d_in[1];
    const float* bk = (const float*)d_in[2];
    const float* ck = (const float*)d_in[3];
    const float* dk = (const float*)d_in[4];
    float* out = (float*)d_out;

    const int B      = in_sizes[0] / 16;       // z is [B,16]
    const int ntiles = B / 32;                 // 32 batch rows per wave-tile

    // persistent: 2048 blocks (8/CU), 4 waves each -> W=8192 waves,
    // 8 tiles/wave at B=2M via grid-stride loop
    int blocks = (ntiles + 3) / 4;
    if (blocks > 2048) blocks = 2048;
    hipLaunchKernelGGL(mave_kernel, dim3(blocks), dim3(256), 0, stream,
                       z, a0, bk, ck, dk, out, ntiles);
}